// Round 12
// baseline (181.610 us; speedup 1.0000x reference)
//
#include <hip/hip_runtime.h>

// GPS layer: GCNConv (self-loops, symmetric norm) + positional-encoding linear.
// N=100000 nodes, E=1600000 edges, IN=128, OUT=64, POS=64.
// Round 11: fuse out_init + gather. Phase A: MFMA pos@Wp (16 nodes/wave) ->
// LDS P. Phase B: CSR gather per node + single f32 out store (no out RMW).
// Saves 51 MB of out traffic + one launch; pos@Wp goes MFMA.

#define THREADS 256
#define K_BUCKETS 512
#define BW 196                 // nodes per bucket; 512*196 = 100352 >= N
#define CHUNK 4096             // edges per hist/binscatter block
#define MAXB 8192              // LDS csr tile cap (mean bucket = 3136 edges)
#define PADK 136               // ushorts per LDS W^T row (128 + 8 pad), 272B = 17*16
#define PADW 72                // ushorts per LDS Wp^T row (64 + 8 pad), 144B = 9*16
#define PADP 68                // floats per LDS P row (64 + 4 pad), 272B

typedef __attribute__((ext_vector_type(8))) short s16x8;
typedef __attribute__((ext_vector_type(4))) float f32x4;

__device__ __forceinline__ unsigned short f2bf(float f) {
    unsigned int u = __float_as_uint(f);
    u = (u + 0x7FFFu + ((u >> 16) & 1u)) >> 16;   // round-to-nearest-even
    return (unsigned short)u;
}
__device__ __forceinline__ float bf2f(unsigned short v) {
    return __uint_as_float(((unsigned int)v) << 16);
}

// bucket_count[k] = 0
__global__ void init512_kernel(int* __restrict__ bucket_count) {
    bucket_count[threadIdx.x] = 0;
}

// per-block LDS histogram of dst buckets -> global bucket_count
__global__ void __launch_bounds__(256)
hist_kernel(const int* __restrict__ dst, int* __restrict__ bucket_count, int E) {
    __shared__ int hist[K_BUCKETS];
    int t = threadIdx.x;
    for (int i = t; i < K_BUCKETS; i += 256) hist[i] = 0;
    __syncthreads();
    int e0 = blockIdx.x * CHUNK;
    for (int i = t; i < CHUNK; i += 256) {
        int e = e0 + i;
        if (e < E) atomicAdd(&hist[dst[e] / BW], 1);
    }
    __syncthreads();
    for (int i = t; i < K_BUCKETS; i += 256)
        if (hist[i]) atomicAdd(&bucket_count[i], hist[i]);
}

// exclusive scan of the 512 bucket counts -> bucket_base; cursor = base
__global__ void scan512_kernel(const int* __restrict__ bucket_count,
                               int* __restrict__ bucket_base,
                               int* __restrict__ bucket_cursor) {
    __shared__ int lds[K_BUCKETS];
    int t = threadIdx.x;
    lds[t] = bucket_count[t];
    __syncthreads();
    for (int off = 1; off < K_BUCKETS; off <<= 1) {
        int v = (t >= off) ? lds[t - off] : 0;
        __syncthreads();
        lds[t] += v;
        __syncthreads();
    }
    int excl = (t > 0) ? lds[t - 1] : 0;
    bucket_base[t] = excl;
    bucket_cursor[t] = excl;
}

// bin edges (src,dst) into bucket-contiguous regions of binned[]
__global__ void __launch_bounds__(256)
binscatter_kernel(const int* __restrict__ src, const int* __restrict__ dst,
                  int* __restrict__ bucket_cursor, int2* __restrict__ binned, int E) {
    __shared__ int hist[K_BUCKETS];
    __shared__ int basew[K_BUCKETS];
    int t = threadIdx.x;
    for (int i = t; i < K_BUCKETS; i += 256) hist[i] = 0;
    __syncthreads();
    int e0 = blockIdx.x * CHUNK;
    for (int i = t; i < CHUNK; i += 256) {
        int e = e0 + i;
        if (e < E) atomicAdd(&hist[dst[e] / BW], 1);
    }
    __syncthreads();
    for (int i = t; i < K_BUCKETS; i += 256) {
        int c = hist[i];
        basew[i] = c ? atomicAdd(&bucket_cursor[i], c) : 0;
    }
    __syncthreads();
    for (int i = t; i < K_BUCKETS; i += 256) hist[i] = 0;
    __syncthreads();
    for (int i = t; i < CHUNK; i += 256) {
        int e = e0 + i;
        if (e < E) {
            int d = dst[e];
            int k = d / BW;
            int r = atomicAdd(&hist[k], 1);
            int2 v; v.x = src[e]; v.y = d;
            binned[basew[k] + r] = v;
        }
    }
}

// one block per bucket: LDS counting-sort its edges into csr order; emit
// csr_src segment plus cnt/offs/dinv for its nodes.
__global__ void __launch_bounds__(256)
bucket_csr_kernel(const int2* __restrict__ binned, const int* __restrict__ bucket_count,
                  const int* __restrict__ bucket_base, int* __restrict__ csr_src,
                  int* __restrict__ cnt, int* __restrict__ offs,
                  float* __restrict__ dinv, int N) {
    __shared__ int cnt_l[256];
    __shared__ int scan_l[256];
    __shared__ int cur_l[256];
    __shared__ int csr_l[MAXB];
    int b = blockIdx.x, t = threadIdx.x;
    int nb = bucket_count[b];
    int base = bucket_base[b];
    int node0 = b * BW;
    cnt_l[t] = 0;
    cur_l[t] = 0;
    __syncthreads();
    for (int i = t; i < nb; i += 256) {
        int2 e = binned[base + i];
        atomicAdd(&cnt_l[e.y - node0], 1);
    }
    __syncthreads();
    scan_l[t] = cnt_l[t];
    __syncthreads();
    for (int off = 1; off < 256; off <<= 1) {
        int v = (t >= off) ? scan_l[t - off] : 0;
        __syncthreads();
        scan_l[t] += v;
        __syncthreads();
    }
    // scan_l = inclusive scan of per-node counts
    for (int i = t; i < nb; i += 256) {
        int2 e = binned[base + i];
        int ld = e.y - node0;
        int pos = (ld ? scan_l[ld - 1] : 0) + atomicAdd(&cur_l[ld], 1);
        csr_l[pos] = e.x;
    }
    __syncthreads();
    for (int i = t; i < nb; i += 256) csr_src[base + i] = csr_l[i];
    if (t < BW) {
        int node = node0 + t;
        if (node < N) {
            int c = cnt_l[t];
            cnt[node] = c;
            offs[node] = base + (t ? scan_l[t - 1] : 0);
            dinv[node] = rsqrtf((float)(c + 1));
        }
    }
}

// h16 = bf16( dinv * (x @ W) ) via MFMA. Per block: 4 waves x 16 x-rows.
__global__ void __launch_bounds__(256)
gemm_xw_kernel(const float* __restrict__ x, const float* __restrict__ W,
               const float* __restrict__ dinv, unsigned short* __restrict__ h16, int N) {
    __shared__ unsigned short ldsWT[64 * PADK];   // 17408 B
    int t = threadIdx.x;
    for (int i = t; i < 128 * 64; i += 256) {
        int k = i >> 6, n = i & 63;
        ldsWT[n * PADK + k] = f2bf(W[i]);         // W[k][n] -> WT[n][k]
    }
    __syncthreads();

    int wave = t >> 6;
    int lane = t & 63;
    int m0 = (blockIdx.x * 4 + wave) * 16;        // 16 x-rows per wave
    if (m0 >= N) return;
    int lm = lane & 15;                           // x-row within tile (D col)
    int kg = lane >> 4;                           // k-group 0..3
    int m = m0 + lm;
    int mload = (m < N) ? m : N - 1;
    const float* xrow = x + (size_t)mload * 128;

    f32x4 acc0 = {0.f, 0.f, 0.f, 0.f};
    f32x4 acc1 = acc0, acc2 = acc0, acc3 = acc0;

#pragma unroll
    for (int ks = 0; ks < 4; ++ks) {
        int k0 = ks * 32 + kg * 8;                // this lane's 8 k-values
        float4 xa = *(const float4*)(xrow + k0);
        float4 xb = *(const float4*)(xrow + k0 + 4);
        s16x8 bfrag;
        bfrag[0] = (short)f2bf(xa.x); bfrag[1] = (short)f2bf(xa.y);
        bfrag[2] = (short)f2bf(xa.z); bfrag[3] = (short)f2bf(xa.w);
        bfrag[4] = (short)f2bf(xb.x); bfrag[5] = (short)f2bf(xb.y);
        bfrag[6] = (short)f2bf(xb.z); bfrag[7] = (short)f2bf(xb.w);
        s16x8 a0 = *(const s16x8*)&ldsWT[(0  + lm) * PADK + k0];
        s16x8 a1 = *(const s16x8*)&ldsWT[(16 + lm) * PADK + k0];
        s16x8 a2 = *(const s16x8*)&ldsWT[(32 + lm) * PADK + k0];
        s16x8 a3 = *(const s16x8*)&ldsWT[(48 + lm) * PADK + k0];
        acc0 = __builtin_amdgcn_mfma_f32_16x16x32_bf16(a0, bfrag, acc0, 0, 0, 0);
        acc1 = __builtin_amdgcn_mfma_f32_16x16x32_bf16(a1, bfrag, acc1, 0, 0, 0);
        acc2 = __builtin_amdgcn_mfma_f32_16x16x32_bf16(a2, bfrag, acc2, 0, 0, 0);
        acc3 = __builtin_amdgcn_mfma_f32_16x16x32_bf16(a3, bfrag, acc3, 0, 0, 0);
    }

    if (m < N) {
        float di = dinv[m];
        ushort4 o;
        unsigned short* hr = h16 + (size_t)m * 64 + kg * 4;
        o.x = f2bf(acc0[0] * di); o.y = f2bf(acc0[1] * di);
        o.z = f2bf(acc0[2] * di); o.w = f2bf(acc0[3] * di);
        *(ushort4*)(hr + 0)  = o;
        o.x = f2bf(acc1[0] * di); o.y = f2bf(acc1[1] * di);
        o.z = f2bf(acc1[2] * di); o.w = f2bf(acc1[3] * di);
        *(ushort4*)(hr + 16) = o;
        o.x = f2bf(acc2[0] * di); o.y = f2bf(acc2[1] * di);
        o.z = f2bf(acc2[2] * di); o.w = f2bf(acc2[3] * di);
        *(ushort4*)(hr + 32) = o;
        o.x = f2bf(acc3[0] * di); o.y = f2bf(acc3[1] * di);
        o.z = f2bf(acc3[2] * di); o.w = f2bf(acc3[3] * di);
        *(ushort4*)(hr + 48) = o;
    }
}

// Fused: out = pos@Wp + (b+bp) + dinv*(h'_self + sum_j h'[src_j])
// Block = 64 nodes, 4 waves. Phase A: MFMA pos@Wp -> LDS P (per-wave 16 nodes).
// Phase B: per-node CSR gather + epilogue, single f32 store (no out pre-read).
__global__ void __launch_bounds__(256)
fused_pg_kernel(const float* __restrict__ pos, const float* __restrict__ Wp,
                const float* __restrict__ b, const float* __restrict__ bp,
                const unsigned short* __restrict__ h16, const float* __restrict__ dinv,
                const int* __restrict__ csr_src, const int* __restrict__ offs,
                const int* __restrict__ cnt, float* __restrict__ out, int N) {
    __shared__ unsigned short ldsWpT[64 * PADW];  // 9216 B
    __shared__ float P[64 * PADP];                // 17408 B
    __shared__ float bb[64];
    int t = threadIdx.x;
    for (int i = t; i < 64 * 64; i += 256) {
        int k = i >> 6, c = i & 63;
        ldsWpT[c * PADW + k] = f2bf(Wp[i]);       // Wp[k][c] -> WpT[c][k]
    }
    if (t < 64) bb[t] = b[t] + bp[t];
    __syncthreads();

    int wave = t >> 6;
    int lane = t & 63;
    int lm = lane & 15;
    int kg = lane >> 4;
    int node0 = blockIdx.x * 64;
    int m = node0 + wave * 16 + lm;
    int mload = (m < N) ? m : N - 1;
    const float* prow = pos + (size_t)mload * 64;

    f32x4 acc0 = {0.f, 0.f, 0.f, 0.f};
    f32x4 acc1 = acc0, acc2 = acc0, acc3 = acc0;
#pragma unroll
    for (int ks = 0; ks < 2; ++ks) {
        int k0 = ks * 32 + kg * 8;
        float4 xa = *(const float4*)(prow + k0);
        float4 xb = *(const float4*)(prow + k0 + 4);
        s16x8 bfrag;
        bfrag[0] = (short)f2bf(xa.x); bfrag[1] = (short)f2bf(xa.y);
        bfrag[2] = (short)f2bf(xa.z); bfrag[3] = (short)f2bf(xa.w);
        bfrag[4] = (short)f2bf(xb.x); bfrag[5] = (short)f2bf(xb.y);
        bfrag[6] = (short)f2bf(xb.z); bfrag[7] = (short)f2bf(xb.w);
        s16x8 a0 = *(const s16x8*)&ldsWpT[(0  + lm) * PADW + k0];
        s16x8 a1 = *(const s16x8*)&ldsWpT[(16 + lm) * PADW + k0];
        s16x8 a2 = *(const s16x8*)&ldsWpT[(32 + lm) * PADW + k0];
        s16x8 a3 = *(const s16x8*)&ldsWpT[(48 + lm) * PADW + k0];
        acc0 = __builtin_amdgcn_mfma_f32_16x16x32_bf16(a0, bfrag, acc0, 0, 0, 0);
        acc1 = __builtin_amdgcn_mfma_f32_16x16x32_bf16(a1, bfrag, acc1, 0, 0, 0);
        acc2 = __builtin_amdgcn_mfma_f32_16x16x32_bf16(a2, bfrag, acc2, 0, 0, 0);
        acc3 = __builtin_amdgcn_mfma_f32_16x16x32_bf16(a3, bfrag, acc3, 0, 0, 0);
    }
    // park P: lane holds ch ct*16+kg*4+reg for node (wave*16+lm)
    {
        float* pr = &P[(wave * 16 + lm) * PADP + kg * 4];
        *(f32x4*)(pr + 0)  = acc0;
        *(f32x4*)(pr + 16) = acc1;
        *(f32x4*)(pr + 32) = acc2;
        *(f32x4*)(pr + 48) = acc3;
    }
    // no __syncthreads needed: each wave reads only its own P rows (lgkmcnt
    // dependency handled by compiler within the wave)

    int c = lane;
    for (int i = 0; i < 16; ++i) {
        int node = node0 + wave * 16 + i;
        if (node >= N) break;
        int beg = offs[node];
        int num = cnt[node];
        const int* idx = csr_src + beg;
        const unsigned short* hc = h16 + c;
        float a0 = 0.f, a1 = 0.f, a2 = 0.f, a3 = 0.f;
        float a4 = 0.f, a5 = 0.f, a6 = 0.f, a7 = 0.f;
        int j = 0;
        for (; j + 8 <= num; j += 8) {
            int s0 = idx[j + 0], s1 = idx[j + 1], s2 = idx[j + 2], s3 = idx[j + 3];
            int s4 = idx[j + 4], s5 = idx[j + 5], s6 = idx[j + 6], s7 = idx[j + 7];
            unsigned short v0 = hc[(size_t)s0 * 64];
            unsigned short v1 = hc[(size_t)s1 * 64];
            unsigned short v2 = hc[(size_t)s2 * 64];
            unsigned short v3 = hc[(size_t)s3 * 64];
            unsigned short v4 = hc[(size_t)s4 * 64];
            unsigned short v5 = hc[(size_t)s5 * 64];
            unsigned short v6 = hc[(size_t)s6 * 64];
            unsigned short v7 = hc[(size_t)s7 * 64];
            a0 += bf2f(v0); a1 += bf2f(v1); a2 += bf2f(v2); a3 += bf2f(v3);
            a4 += bf2f(v4); a5 += bf2f(v5); a6 += bf2f(v6); a7 += bf2f(v7);
        }
        for (; j + 4 <= num; j += 4) {
            int s0 = idx[j + 0], s1 = idx[j + 1], s2 = idx[j + 2], s3 = idx[j + 3];
            unsigned short v0 = hc[(size_t)s0 * 64];
            unsigned short v1 = hc[(size_t)s1 * 64];
            unsigned short v2 = hc[(size_t)s2 * 64];
            unsigned short v3 = hc[(size_t)s3 * 64];
            a0 += bf2f(v0); a1 += bf2f(v1); a2 += bf2f(v2); a3 += bf2f(v3);
        }
        for (; j < num; ++j) a0 += bf2f(hc[(size_t)idx[j] * 64]);
        float gsum = ((a0 + a1) + (a2 + a3)) + ((a4 + a5) + (a6 + a7));
        float self = bf2f(h16[(size_t)node * 64 + c]);
        float o = P[(wave * 16 + i) * PADP + c] + bb[c]
                + dinv[node] * (self + gsum);
        out[(size_t)node * 64 + c] = o;
    }
}

extern "C" void kernel_launch(void* const* d_in, const int* in_sizes, int n_in,
                              void* d_out, int out_size, void* d_ws, size_t ws_size,
                              hipStream_t stream) {
    const float* x   = (const float*)d_in[0];   // [N,128]
    const int*   ei  = (const int*)d_in[1];     // [2,E]
    const float* pos = (const float*)d_in[2];   // [N,64]
    const float* W   = (const float*)d_in[3];   // [128,64]
    const float* b   = (const float*)d_in[4];   // [64]
    const float* Wp  = (const float*)d_in[5];   // [64,64]
    const float* bp  = (const float*)d_in[6];   // [64]
    float* out = (float*)d_out;

    const int N = in_sizes[0] / 128;            // 100000
    const int E = in_sizes[1] / 2;              // 1600000
    const int* srcp = ei;
    const int* dstp = ei + E;

    // workspace layout (4B aligned):
    //   h16 [N*64 ushort = N*32 float-slots]  -- aliased as binned[E int2]
    //   dinv [N] | cnt [N] | offs [N] | bucket_count/base/cursor [512 each]
    //   csr_src [E]
    unsigned short* h16  = (unsigned short*)d_ws;
    float* dinv          = (float*)d_ws + (size_t)N * 32;
    int*   cnt           = (int*)(dinv + N);
    int*   offs          = cnt + N;
    int*   bucket_count  = offs + N;
    int*   bucket_base   = bucket_count + K_BUCKETS;
    int*   bucket_cursor = bucket_base + K_BUCKETS;
    int*   csr_src       = bucket_cursor + K_BUCKETS;
    int2*  binned        = (int2*)d_ws;          // E*8B == N*64*2B exactly

    int nbHB = (E + CHUNK - 1) / CHUNK;          // 391 blocks

    init512_kernel<<<1, K_BUCKETS, 0, stream>>>(bucket_count);
    hist_kernel<<<nbHB, THREADS, 0, stream>>>(dstp, bucket_count, E);
    scan512_kernel<<<1, K_BUCKETS, 0, stream>>>(bucket_count, bucket_base, bucket_cursor);
    binscatter_kernel<<<nbHB, THREADS, 0, stream>>>(srcp, dstp, bucket_cursor, binned, E);
    bucket_csr_kernel<<<K_BUCKETS, THREADS, 0, stream>>>(binned, bucket_count, bucket_base,
                                                         csr_src, cnt, offs, dinv, N);

    int nbGm = (N + 63) / 64;                    // 4 waves x 16 rows per block
    gemm_xw_kernel<<<nbGm, THREADS, 0, stream>>>(x, W, dinv, h16, N);  // overwrites binned (done)

    int nbF = (N + 63) / 64;                     // 64 nodes per block
    fused_pg_kernel<<<nbF, THREADS, 0, stream>>>(pos, Wp, b, bp, h16, dinv,
                                                 csr_src, offs, cnt, out, N);
}

// Round 14
// 147.798 us; speedup vs baseline: 1.2288x; 1.2288x over previous
//
#include <hip/hip_runtime.h>

// GPS layer: GCNConv (self-loops, symmetric norm) + positional-encoding linear.
// N=100000 nodes, E=1600000 edges, IN=128, OUT=64, POS=64.
// Round 13: revert round-12 fusion (27KB LDS halved occupancy for the
// latency-bound gather: 69%->34%). Keep split kernels; out_init now MFMA
// (WpT bf16 in 9.2KB LDS, results stored from registers, no P buffer).

#define THREADS 256
#define K_BUCKETS 512
#define BW 196                 // nodes per bucket; 512*196 = 100352 >= N
#define CHUNK 4096             // edges per hist/binscatter block
#define MAXB 8192              // LDS csr tile cap (mean bucket = 3136 edges)
#define PADK 136               // ushorts per LDS W^T row (128 + 8 pad)
#define PADW 72                // ushorts per LDS Wp^T row (64 + 8 pad)

typedef __attribute__((ext_vector_type(8))) short s16x8;
typedef __attribute__((ext_vector_type(4))) float f32x4;

__device__ __forceinline__ unsigned short f2bf(float f) {
    unsigned int u = __float_as_uint(f);
    u = (u + 0x7FFFu + ((u >> 16) & 1u)) >> 16;   // round-to-nearest-even
    return (unsigned short)u;
}
__device__ __forceinline__ float bf2f(unsigned short v) {
    return __uint_as_float(((unsigned int)v) << 16);
}

// bucket_count[k] = 0
__global__ void init512_kernel(int* __restrict__ bucket_count) {
    bucket_count[threadIdx.x] = 0;
}

// per-block LDS histogram of dst buckets -> global bucket_count
__global__ void __launch_bounds__(256)
hist_kernel(const int* __restrict__ dst, int* __restrict__ bucket_count, int E) {
    __shared__ int hist[K_BUCKETS];
    int t = threadIdx.x;
    for (int i = t; i < K_BUCKETS; i += 256) hist[i] = 0;
    __syncthreads();
    int e0 = blockIdx.x * CHUNK;
    for (int i = t; i < CHUNK; i += 256) {
        int e = e0 + i;
        if (e < E) atomicAdd(&hist[dst[e] / BW], 1);
    }
    __syncthreads();
    for (int i = t; i < K_BUCKETS; i += 256)
        if (hist[i]) atomicAdd(&bucket_count[i], hist[i]);
}

// exclusive scan of the 512 bucket counts -> bucket_base; cursor = base
__global__ void scan512_kernel(const int* __restrict__ bucket_count,
                               int* __restrict__ bucket_base,
                               int* __restrict__ bucket_cursor) {
    __shared__ int lds[K_BUCKETS];
    int t = threadIdx.x;
    lds[t] = bucket_count[t];
    __syncthreads();
    for (int off = 1; off < K_BUCKETS; off <<= 1) {
        int v = (t >= off) ? lds[t - off] : 0;
        __syncthreads();
        lds[t] += v;
        __syncthreads();
    }
    int excl = (t > 0) ? lds[t - 1] : 0;
    bucket_base[t] = excl;
    bucket_cursor[t] = excl;
}

// bin edges (src,dst) into bucket-contiguous regions of binned[]
__global__ void __launch_bounds__(256)
binscatter_kernel(const int* __restrict__ src, const int* __restrict__ dst,
                  int* __restrict__ bucket_cursor, int2* __restrict__ binned, int E) {
    __shared__ int hist[K_BUCKETS];
    __shared__ int basew[K_BUCKETS];
    int t = threadIdx.x;
    for (int i = t; i < K_BUCKETS; i += 256) hist[i] = 0;
    __syncthreads();
    int e0 = blockIdx.x * CHUNK;
    for (int i = t; i < CHUNK; i += 256) {
        int e = e0 + i;
        if (e < E) atomicAdd(&hist[dst[e] / BW], 1);
    }
    __syncthreads();
    for (int i = t; i < K_BUCKETS; i += 256) {
        int c = hist[i];
        basew[i] = c ? atomicAdd(&bucket_cursor[i], c) : 0;
    }
    __syncthreads();
    for (int i = t; i < K_BUCKETS; i += 256) hist[i] = 0;
    __syncthreads();
    for (int i = t; i < CHUNK; i += 256) {
        int e = e0 + i;
        if (e < E) {
            int d = dst[e];
            int k = d / BW;
            int r = atomicAdd(&hist[k], 1);
            int2 v; v.x = src[e]; v.y = d;
            binned[basew[k] + r] = v;
        }
    }
}

// one block per bucket: LDS counting-sort its edges into csr order; emit
// csr_src segment plus cnt/offs/dinv for its nodes.
__global__ void __launch_bounds__(256)
bucket_csr_kernel(const int2* __restrict__ binned, const int* __restrict__ bucket_count,
                  const int* __restrict__ bucket_base, int* __restrict__ csr_src,
                  int* __restrict__ cnt, int* __restrict__ offs,
                  float* __restrict__ dinv, int N) {
    __shared__ int cnt_l[256];
    __shared__ int scan_l[256];
    __shared__ int cur_l[256];
    __shared__ int csr_l[MAXB];
    int b = blockIdx.x, t = threadIdx.x;
    int nb = bucket_count[b];
    int base = bucket_base[b];
    int node0 = b * BW;
    cnt_l[t] = 0;
    cur_l[t] = 0;
    __syncthreads();
    for (int i = t; i < nb; i += 256) {
        int2 e = binned[base + i];
        atomicAdd(&cnt_l[e.y - node0], 1);
    }
    __syncthreads();
    scan_l[t] = cnt_l[t];
    __syncthreads();
    for (int off = 1; off < 256; off <<= 1) {
        int v = (t >= off) ? scan_l[t - off] : 0;
        __syncthreads();
        scan_l[t] += v;
        __syncthreads();
    }
    // scan_l = inclusive scan of per-node counts
    for (int i = t; i < nb; i += 256) {
        int2 e = binned[base + i];
        int ld = e.y - node0;
        int pos = (ld ? scan_l[ld - 1] : 0) + atomicAdd(&cur_l[ld], 1);
        csr_l[pos] = e.x;
    }
    __syncthreads();
    for (int i = t; i < nb; i += 256) csr_src[base + i] = csr_l[i];
    if (t < BW) {
        int node = node0 + t;
        if (node < N) {
            int c = cnt_l[t];
            cnt[node] = c;
            offs[node] = base + (t ? scan_l[t - 1] : 0);
            dinv[node] = rsqrtf((float)(c + 1));
        }
    }
}

// h16 = bf16( dinv * (x @ W) ) via MFMA. Per block: 4 waves x 16 x-rows.
__global__ void __launch_bounds__(256)
gemm_xw_kernel(const float* __restrict__ x, const float* __restrict__ W,
               const float* __restrict__ dinv, unsigned short* __restrict__ h16, int N) {
    __shared__ unsigned short ldsWT[64 * PADK];   // 17408 B
    int t = threadIdx.x;
    for (int i = t; i < 128 * 64; i += 256) {
        int k = i >> 6, n = i & 63;
        ldsWT[n * PADK + k] = f2bf(W[i]);         // W[k][n] -> WT[n][k]
    }
    __syncthreads();

    int wave = t >> 6;
    int lane = t & 63;
    int m0 = (blockIdx.x * 4 + wave) * 16;        // 16 x-rows per wave
    if (m0 >= N) return;
    int lm = lane & 15;                           // x-row within tile (D col)
    int kg = lane >> 4;                           // k-group 0..3
    int m = m0 + lm;
    int mload = (m < N) ? m : N - 1;
    const float* xrow = x + (size_t)mload * 128;

    f32x4 acc0 = {0.f, 0.f, 0.f, 0.f};
    f32x4 acc1 = acc0, acc2 = acc0, acc3 = acc0;

#pragma unroll
    for (int ks = 0; ks < 4; ++ks) {
        int k0 = ks * 32 + kg * 8;                // this lane's 8 k-values
        float4 xa = *(const float4*)(xrow + k0);
        float4 xb = *(const float4*)(xrow + k0 + 4);
        s16x8 bfrag;
        bfrag[0] = (short)f2bf(xa.x); bfrag[1] = (short)f2bf(xa.y);
        bfrag[2] = (short)f2bf(xa.z); bfrag[3] = (short)f2bf(xa.w);
        bfrag[4] = (short)f2bf(xb.x); bfrag[5] = (short)f2bf(xb.y);
        bfrag[6] = (short)f2bf(xb.z); bfrag[7] = (short)f2bf(xb.w);
        s16x8 a0 = *(const s16x8*)&ldsWT[(0  + lm) * PADK + k0];
        s16x8 a1 = *(const s16x8*)&ldsWT[(16 + lm) * PADK + k0];
        s16x8 a2 = *(const s16x8*)&ldsWT[(32 + lm) * PADK + k0];
        s16x8 a3 = *(const s16x8*)&ldsWT[(48 + lm) * PADK + k0];
        acc0 = __builtin_amdgcn_mfma_f32_16x16x32_bf16(a0, bfrag, acc0, 0, 0, 0);
        acc1 = __builtin_amdgcn_mfma_f32_16x16x32_bf16(a1, bfrag, acc1, 0, 0, 0);
        acc2 = __builtin_amdgcn_mfma_f32_16x16x32_bf16(a2, bfrag, acc2, 0, 0, 0);
        acc3 = __builtin_amdgcn_mfma_f32_16x16x32_bf16(a3, bfrag, acc3, 0, 0, 0);
    }

    if (m < N) {
        float di = dinv[m];
        ushort4 o;
        unsigned short* hr = h16 + (size_t)m * 64 + kg * 4;
        o.x = f2bf(acc0[0] * di); o.y = f2bf(acc0[1] * di);
        o.z = f2bf(acc0[2] * di); o.w = f2bf(acc0[3] * di);
        *(ushort4*)(hr + 0)  = o;
        o.x = f2bf(acc1[0] * di); o.y = f2bf(acc1[1] * di);
        o.z = f2bf(acc1[2] * di); o.w = f2bf(acc1[3] * di);
        *(ushort4*)(hr + 16) = o;
        o.x = f2bf(acc2[0] * di); o.y = f2bf(acc2[1] * di);
        o.z = f2bf(acc2[2] * di); o.w = f2bf(acc2[3] * di);
        *(ushort4*)(hr + 32) = o;
        o.x = f2bf(acc3[0] * di); o.y = f2bf(acc3[1] * di);
        o.z = f2bf(acc3[2] * di); o.w = f2bf(acc3[3] * di);
        *(ushort4*)(hr + 48) = o;
    }
}

// out = pos@Wp + (b+bp) + dinv*h'_self  via MFMA (gather adds neighbors later).
// 4 waves x 16 pos-rows per block; WpT bf16 in LDS (9.2KB); no P LDS buffer.
__global__ void __launch_bounds__(256)
out_init_kernel(const float* __restrict__ pos, const float* __restrict__ Wp,
                const float* __restrict__ b, const float* __restrict__ bp,
                const unsigned short* __restrict__ h16, const float* __restrict__ dinv,
                float* __restrict__ out, int N) {
    __shared__ unsigned short ldsWpT[64 * PADW];  // 9216 B
    __shared__ float bb[64];
    int t = threadIdx.x;
    for (int i = t; i < 64 * 64; i += 256) {
        int k = i >> 6, c = i & 63;
        ldsWpT[c * PADW + k] = f2bf(Wp[i]);       // Wp[k][c] -> WpT[c][k]
    }
    if (t < 64) bb[t] = b[t] + bp[t];
    __syncthreads();

    int wave = t >> 6;
    int lane = t & 63;
    int lm = lane & 15;
    int kg = lane >> 4;
    int m = blockIdx.x * 64 + wave * 16 + lm;
    int mload = (m < N) ? m : N - 1;
    const float* prow = pos + (size_t)mload * 64;

    f32x4 acc0 = {0.f, 0.f, 0.f, 0.f};
    f32x4 acc1 = acc0, acc2 = acc0, acc3 = acc0;
#pragma unroll
    for (int ks = 0; ks < 2; ++ks) {
        int k0 = ks * 32 + kg * 8;
        float4 xa = *(const float4*)(prow + k0);
        float4 xb = *(const float4*)(prow + k0 + 4);
        s16x8 bfrag;
        bfrag[0] = (short)f2bf(xa.x); bfrag[1] = (short)f2bf(xa.y);
        bfrag[2] = (short)f2bf(xa.z); bfrag[3] = (short)f2bf(xa.w);
        bfrag[4] = (short)f2bf(xb.x); bfrag[5] = (short)f2bf(xb.y);
        bfrag[6] = (short)f2bf(xb.z); bfrag[7] = (short)f2bf(xb.w);
        s16x8 a0 = *(const s16x8*)&ldsWpT[(0  + lm) * PADW + k0];
        s16x8 a1 = *(const s16x8*)&ldsWpT[(16 + lm) * PADW + k0];
        s16x8 a2 = *(const s16x8*)&ldsWpT[(32 + lm) * PADW + k0];
        s16x8 a3 = *(const s16x8*)&ldsWpT[(48 + lm) * PADW + k0];
        acc0 = __builtin_amdgcn_mfma_f32_16x16x32_bf16(a0, bfrag, acc0, 0, 0, 0);
        acc1 = __builtin_amdgcn_mfma_f32_16x16x32_bf16(a1, bfrag, acc1, 0, 0, 0);
        acc2 = __builtin_amdgcn_mfma_f32_16x16x32_bf16(a2, bfrag, acc2, 0, 0, 0);
        acc3 = __builtin_amdgcn_mfma_f32_16x16x32_bf16(a3, bfrag, acc3, 0, 0, 0);
    }

    if (m < N) {
        float di = dinv[m];
        float* orow = out + (size_t)m * 64;
        const unsigned short* hr = h16 + (size_t)m * 64;
        int c0 = kg * 4;
        f32x4 o;
        ushort4 hv;
        hv = *(const ushort4*)(hr + c0);
        o[0] = acc0[0] + bb[c0 + 0] + di * bf2f(hv.x);
        o[1] = acc0[1] + bb[c0 + 1] + di * bf2f(hv.y);
        o[2] = acc0[2] + bb[c0 + 2] + di * bf2f(hv.z);
        o[3] = acc0[3] + bb[c0 + 3] + di * bf2f(hv.w);
        *(f32x4*)(orow + c0) = o;
        hv = *(const ushort4*)(hr + 16 + c0);
        o[0] = acc1[0] + bb[16 + c0 + 0] + di * bf2f(hv.x);
        o[1] = acc1[1] + bb[16 + c0 + 1] + di * bf2f(hv.y);
        o[2] = acc1[2] + bb[16 + c0 + 2] + di * bf2f(hv.z);
        o[3] = acc1[3] + bb[16 + c0 + 3] + di * bf2f(hv.w);
        *(f32x4*)(orow + 16 + c0) = o;
        hv = *(const ushort4*)(hr + 32 + c0);
        o[0] = acc2[0] + bb[32 + c0 + 0] + di * bf2f(hv.x);
        o[1] = acc2[1] + bb[32 + c0 + 1] + di * bf2f(hv.y);
        o[2] = acc2[2] + bb[32 + c0 + 2] + di * bf2f(hv.z);
        o[3] = acc2[3] + bb[32 + c0 + 3] + di * bf2f(hv.w);
        *(f32x4*)(orow + 32 + c0) = o;
        hv = *(const ushort4*)(hr + 48 + c0);
        o[0] = acc3[0] + bb[48 + c0 + 0] + di * bf2f(hv.x);
        o[1] = acc3[1] + bb[48 + c0 + 1] + di * bf2f(hv.y);
        o[2] = acc3[2] + bb[48 + c0 + 2] + di * bf2f(hv.z);
        o[3] = acc3[3] + bb[48 + c0 + 3] + di * bf2f(hv.w);
        *(f32x4*)(orow + 48 + c0) = o;
    }
}

// one wave per node: out[d][c] += dinv[d] * sum_j h'[s_j][c]   (h' bf16)
// Unrolled x8/x4 so 8 (resp 4) h-row loads are in flight per batch.
__global__ void __launch_bounds__(256)
gather_kernel(const int* __restrict__ csr_src, const int* __restrict__ offs,
              const int* __restrict__ cnt, const unsigned short* __restrict__ h16,
              const float* __restrict__ dinv, float* __restrict__ out, int N) {
    int wid = (int)((blockIdx.x * (size_t)blockDim.x + threadIdx.x) >> 6);
    int c = threadIdx.x & 63;
    if (wid >= N) return;
    int beg = offs[wid];
    int num = cnt[wid];
    const int* idx = csr_src + beg;
    const unsigned short* hc = h16 + c;
    float a0 = 0.f, a1 = 0.f, a2 = 0.f, a3 = 0.f;
    float a4 = 0.f, a5 = 0.f, a6 = 0.f, a7 = 0.f;
    int j = 0;
    for (; j + 8 <= num; j += 8) {
        int s0 = idx[j + 0], s1 = idx[j + 1], s2 = idx[j + 2], s3 = idx[j + 3];
        int s4 = idx[j + 4], s5 = idx[j + 5], s6 = idx[j + 6], s7 = idx[j + 7];
        unsigned short v0 = hc[(size_t)s0 * 64];
        unsigned short v1 = hc[(size_t)s1 * 64];
        unsigned short v2 = hc[(size_t)s2 * 64];
        unsigned short v3 = hc[(size_t)s3 * 64];
        unsigned short v4 = hc[(size_t)s4 * 64];
        unsigned short v5 = hc[(size_t)s5 * 64];
        unsigned short v6 = hc[(size_t)s6 * 64];
        unsigned short v7 = hc[(size_t)s7 * 64];
        a0 += bf2f(v0); a1 += bf2f(v1); a2 += bf2f(v2); a3 += bf2f(v3);
        a4 += bf2f(v4); a5 += bf2f(v5); a6 += bf2f(v6); a7 += bf2f(v7);
    }
    for (; j + 4 <= num; j += 4) {
        int s0 = idx[j + 0], s1 = idx[j + 1], s2 = idx[j + 2], s3 = idx[j + 3];
        unsigned short v0 = hc[(size_t)s0 * 64];
        unsigned short v1 = hc[(size_t)s1 * 64];
        unsigned short v2 = hc[(size_t)s2 * 64];
        unsigned short v3 = hc[(size_t)s3 * 64];
        a0 += bf2f(v0); a1 += bf2f(v1); a2 += bf2f(v2); a3 += bf2f(v3);
    }
    for (; j < num; ++j) a0 += bf2f(hc[(size_t)idx[j] * 64]);
    float acc = ((a0 + a1) + (a2 + a3)) + ((a4 + a5) + (a6 + a7));
    size_t o = (size_t)wid * 64 + c;
    out[o] = fmaf(dinv[wid], acc, out[o]);  // non-atomic: this wave owns row wid
}

extern "C" void kernel_launch(void* const* d_in, const int* in_sizes, int n_in,
                              void* d_out, int out_size, void* d_ws, size_t ws_size,
                              hipStream_t stream) {
    const float* x   = (const float*)d_in[0];   // [N,128]
    const int*   ei  = (const int*)d_in[1];     // [2,E]
    const float* pos = (const float*)d_in[2];   // [N,64]
    const float* W   = (const float*)d_in[3];   // [128,64]
    const float* b   = (const float*)d_in[4];   // [64]
    const float* Wp  = (const float*)d_in[5];   // [64,64]
    const float* bp  = (const float*)d_in[6];   // [64]
    float* out = (float*)d_out;

    const int N = in_sizes[0] / 128;            // 100000
    const int E = in_sizes[1] / 2;              // 1600000
    const int* srcp = ei;
    const int* dstp = ei + E;

    // workspace layout (4B aligned):
    //   h16 [N*64 ushort = N*32 float-slots]  -- aliased as binned[E int2]
    //   dinv [N] | cnt [N] | offs [N] | bucket_count/base/cursor [512 each]
    //   csr_src [E]
    unsigned short* h16  = (unsigned short*)d_ws;
    float* dinv          = (float*)d_ws + (size_t)N * 32;
    int*   cnt           = (int*)(dinv + N);
    int*   offs          = cnt + N;
    int*   bucket_count  = offs + N;
    int*   bucket_base   = bucket_count + K_BUCKETS;
    int*   bucket_cursor = bucket_base + K_BUCKETS;
    int*   csr_src       = bucket_cursor + K_BUCKETS;
    int2*  binned        = (int2*)d_ws;          // E*8B == N*64*2B exactly

    int nbHB = (E + CHUNK - 1) / CHUNK;          // 391 blocks

    init512_kernel<<<1, K_BUCKETS, 0, stream>>>(bucket_count);
    hist_kernel<<<nbHB, THREADS, 0, stream>>>(dstp, bucket_count, E);
    scan512_kernel<<<1, K_BUCKETS, 0, stream>>>(bucket_count, bucket_base, bucket_cursor);
    binscatter_kernel<<<nbHB, THREADS, 0, stream>>>(srcp, dstp, bucket_cursor, binned, E);
    bucket_csr_kernel<<<K_BUCKETS, THREADS, 0, stream>>>(binned, bucket_count, bucket_base,
                                                         csr_src, cnt, offs, dinv, N);

    int nbGm = (N + 63) / 64;                    // 4 waves x 16 rows per block
    gemm_xw_kernel<<<nbGm, THREADS, 0, stream>>>(x, W, dinv, h16, N);  // overwrites binned (done)

    int nbO = (N + 63) / 64;                     // 4 waves x 16 rows per block
    out_init_kernel<<<nbO, THREADS, 0, stream>>>(pos, Wp, b, bp, h16, dinv, out, N);

    long long totalGC = (long long)N * 64;
    int nbGa = (int)((totalGC + THREADS - 1) / THREADS);
    gather_kernel<<<nbGa, THREADS, 0, stream>>>(csr_src, offs, cnt, h16, dinv, out, N);
}